// Round 9
// baseline (312.563 us; speedup 1.0000x reference)
//
#include <hip/hip_runtime.h>
#include <math.h>

// Shapes (fixed): B=32, M=2, C=256, H=W=16, N=256, DIM=256, THR=0.1, RATIO=0.8
// out: fused (32,256,16,16) = 2,097,152 floats, then auto_enc_loss (1 float)
//
// R9: conv GEMMs load B (weights) direct global->register (lanes {l,l+16,..}
// hit one 64B segment/row) with register double-buffer; LDS holds only A
// (2x16KB). ansbmt folded into prep via closed-form slot recompute; score
// cf-phases folded into encrec; rec-phase score conv de-normalized
// (sc*conv(rec)+sh*P) so it needs no min/max. 5 launches.

typedef __attribute__((ext_vector_type(8))) short short8;
typedef __attribute__((ext_vector_type(4))) float f32x4;

__device__ __forceinline__ void gload_lds16(const void* g, void* l) {
  __builtin_amdgcn_global_load_lds(
      (const __attribute__((address_space(1))) void*)g,
      (__attribute__((address_space(3))) void*)l, 16, 0, 0);
}

__device__ __forceinline__ unsigned short f2bf(float f) {
  unsigned u = __float_as_uint(f);
  unsigned r = (u + 0x7FFFu + ((u >> 16) & 1u)) >> 16;  // RNE
  return (unsigned short)r;
}

__device__ __forceinline__ unsigned mapf(float f) {
  unsigned u = __float_as_uint(f);
  return (u & 0x80000000u) ? ~u : (u | 0x80000000u);
}
__device__ __forceinline__ float unmapf(unsigned u) {
  unsigned v = (u & 0x80000000u) ? (u & 0x7fffffffu) : ~u;
  return __uint_as_float(v);
}

// closed-form slot counts for batch b (same arithmetic as reference)
__device__ __forceinline__ void slot_counts(const float* __restrict__ fv, int b,
                                            int t, int* shm, int& c0o, int& c1o) {
  const float v0 = fv[(size_t)b * 512 + t];
  const float v1 = fv[(size_t)b * 512 + 256 + t];
  const unsigned long long bal0 = __ballot(v0 > 0.1f);
  const unsigned long long bal1 = __ballot(v1 > 0.1f);
  const int wid = t >> 6, lane = t & 63;
  if (lane == 0) { shm[wid] = __popcll(bal0); shm[4 + wid] = __popcll(bal1); }
  __syncthreads();
  int c0 = shm[0] + shm[1] + shm[2] + shm[3];
  int c1 = shm[4] + shm[5] + shm[6] + shm[7];
  int total = c0 + c1;
  if (total > 256) {
    int a0 = (int)rintf(256.0f * (float)c0 / (float)total);
    c0 = a0; c1 = 256 - a0;
  }
  c0o = max(c0, 0); c1o = max(c1, 0);
}

// ---------------- mega-prep: pack | wrk | halos | ansb | bmt | wsum9+init
__global__ __launch_bounds__(256) void prep_k(
    const float* __restrict__ cf, const float* __restrict__ we,
    const float* __restrict__ wd, const float* __restrict__ fv,
    const float* __restrict__ fs, const float* __restrict__ fd,
    const float* __restrict__ wval,
    unsigned short* __restrict__ Xp, unsigned short* __restrict__ WrE,
    unsigned short* __restrict__ WrD, unsigned short* __restrict__ Ans,
    unsigned short* __restrict__ BmT, unsigned short* __restrict__ Recp,
    float* __restrict__ wsum9, float* __restrict__ lacc,
    unsigned* __restrict__ mm) {
  __shared__ float sIn[4096];
  __shared__ int shm[8];
  const int bx = blockIdx.x, t = threadIdx.x;
  if (bx < 2048) {                       // pack: cf NCHW f32 -> padded NHWC bf16
    int idx = bx * 256 + t;
    int p = idx & 255, ch = (idx >> 8) & 31, img = idx >> 13;
    int ic0 = ch * 8;
    const float* sp = cf + (size_t)img * 65536 + (size_t)ic0 * 256 + p;
    unsigned short h[8];
#pragma unroll
    for (int i = 0; i < 8; ++i) h[i] = f2bf(sp[i * 256]);
    int y = p >> 4, x = p & 15;
    uint4 u;
    u.x = h[0] | (h[1] << 16); u.y = h[2] | (h[3] << 16);
    u.z = h[4] | (h[5] << 16); u.w = h[6] | (h[7] << 16);
    *(uint4*)&Xp[(size_t)img * 82944 + (size_t)(y * 18 + x + 19) * 256 + ic0] = u;
  } else if (bx < 2624) {                // wrk: OIHW f32 -> Wr[oc][s][ic] bf16
    int idx = (bx - 2048) * 256 + t;
    int ch = idx & 31, rest = idx >> 5;
    int s = rest % 9, ocx = rest / 9;
    int oc = ocx & 255, cv = ocx >> 8;
    const float* w = cv ? wd : we;
    unsigned short* o = cv ? WrD : WrE;
    int ic0 = ch * 8;
    unsigned short h[8];
#pragma unroll
    for (int i = 0; i < 8; ++i) h[i] = f2bf(w[(size_t)oc * 2304 + (ic0 + i) * 9 + s]);
    uint4 u;
    u.x = h[0] | (h[1] << 16); u.y = h[2] | (h[3] << 16);
    u.z = h[4] | (h[5] << 16); u.w = h[6] | (h[7] << 16);
    *(uint4*)&o[(size_t)oc * 2304 + s * 256 + ic0] = u;
  } else if (bx < 2752) {                // halo zero: Xp 0..63 | Midp (contig) 64..127
    int img = bx - 2624;
    uint4* base = (uint4*)Xp + (size_t)img * 10368;
    uint4 z; z.x = z.y = z.z = z.w = 0;
    for (int it = t; it < 2176; it += 256) {
      int px = it >> 5, c = it & 31;
      int y, x;
      if (px < 18)      { y = 0;  x = px; }
      else if (px < 36) { y = 17; x = px - 18; }
      else if (px < 52) { y = px - 35; x = 0; }
      else              { y = px - 51; x = 17; }
      base[(y * 18 + x) * 32 + c] = z;
    }
  } else if (bx < 2784) {                // Recp halo zero (32 imgs)
    int img = bx - 2752;
    uint4* base = (uint4*)Recp + (size_t)img * 10368;
    uint4 z; z.x = z.y = z.z = z.w = 0;
    for (int it = t; it < 2176; it += 256) {
      int px = it >> 5, c = it & 31;
      int y, x;
      if (px < 18)      { y = 0;  x = px; }
      else if (px < 36) { y = 17; x = px - 18; }
      else if (px < 52) { y = px - 35; x = 0; }
      else              { y = px - 51; x = 17; }
      base[(y * 18 + x) * 32 + c] = z;
    }
  } else if (bx < 3808) {                // ansb: Ans[b][c][j] = ns[c][j]*v_j
    int bi = bx - 2784;
    int b = bi >> 5, cbase = (bi & 31) * 8;
    int c0, c1;
    slot_counts(fv, b, t, shm, c0, c1);
    int c = cbase + (t >> 5), ch = t & 31, j0 = ch * 8;
    int m = -1, r = 0;
    if (c < c0) { m = 0; r = c; }
    else if (c - c0 < c1) { m = 1; r = c - c0; }
    unsigned short h[8] = {0, 0, 0, 0, 0, 0, 0, 0};
    if (m >= 0) {
      const float* fp = fs + (((size_t)b * 2 + m) * 256 + r) * 256 + j0;
#pragma unroll
      for (int i = 0; i < 8; ++i) {
        int j = j0 + i;
        float vj = 0.f;
        if (j < c0) vj = fv[(size_t)b * 512 + j];
        else if (j - c0 < c1) vj = fv[(size_t)b * 512 + 256 + (j - c0)];
        h[i] = f2bf(fp[i] * vj);
      }
    }
    uint4 u;
    u.x = h[0] | (h[1] << 16); u.y = h[2] | (h[3] << 16);
    u.z = h[4] | (h[5] << 16); u.w = h[6] | (h[7] << 16);
    *(uint4*)&Ans[(size_t)b * 65536 + c * 256 + j0] = u;
  } else if (bx < 3936) {                // bmt: BmT[b][p][j] = fd[b,m_p,j,r_p]
    int bi = bx - 3808;
    int b = bi >> 2, bz = bi & 3;
    int c0, c1;
    slot_counts(fv, b, t, shm, c0, c1);
    int m_p = -1, r_p = 0;
    if (t < c0) { m_p = 0; r_p = t; }
    else if (t - c0 < c1) { m_p = 1; r_p = t - c0; }
    for (int jg = bz * 8; jg < bz * 8 + 8; ++jg) {
      __syncthreads();
#pragma unroll
      for (int u = 0; u < 4; ++u) {
        int q = t * 4 + u;
        int rr = q >> 6, w = q & 63;
        int m = rr >> 3, i = rr & 7;
        float4 f = ((const float4*)fd)[((size_t)(b * 2 + m) * 256 + jg * 8 + i) * 64 + w];
        *(float4*)&sIn[i * 512 + m * 256 + w * 4] = f;
      }
      __syncthreads();
      unsigned short h[8] = {0, 0, 0, 0, 0, 0, 0, 0};
      if (m_p >= 0) {
#pragma unroll
        for (int i = 0; i < 8; ++i) h[i] = f2bf(sIn[i * 512 + m_p * 256 + r_p]);
      }
      uint4 u;
      u.x = h[0] | (h[1] << 16); u.y = h[2] | (h[3] << 16);
      u.z = h[4] | (h[5] << 16); u.w = h[6] | (h[7] << 16);
      *(uint4*)&BmT[(size_t)b * 65536 + t * 256 + jg * 8] = u;
    }
  } else {                               // wsum9 + init
    for (int j = 0; j < 9; ++j) {
      float v = wval[t * 9 + j];
#pragma unroll
      for (int off = 32; off; off >>= 1) v += __shfl_down(v, off);
      if ((t & 63) == 0) sIn[t >> 6] = v;
      __syncthreads();
      if (t == 0) wsum9[j] = sIn[0] + sIn[1] + sIn[2] + sIn[3];
      __syncthreads();
    }
    if (t == 0) { lacc[0] = 0.f; mm[0] = 0xFFFFFFFFu; mm[1] = 0u; }
  }
}

// ======= encrec: [0,256) enc conv | [256,384) recgemm | [384,448) score_cf
__global__ __launch_bounds__(512, 4) void encrec_k(
    const unsigned short* __restrict__ Xin, const unsigned short* __restrict__ Wr,
    const float* __restrict__ bias, unsigned short* __restrict__ Midp,
    const unsigned short* __restrict__ BmT, const unsigned short* __restrict__ Ans,
    unsigned short* __restrict__ Recp, const float* __restrict__ cf,
    const float* __restrict__ wval, float* __restrict__ sraw) {
  __shared__ __align__(16) char S[32768];
  const int t = threadIdx.x, lane = t & 63, wave = t >> 6;
  const int L = blockIdx.x;

  if (L >= 384) {                        // ---- score_cf: (b, m) 1-ch conv on cf
    const int sb = L - 384;
    const int b = sb >> 1, m = sb & 1;
    const int half = t >> 8, px = t & 255;
    const int row = px >> 4, col = px & 15;
    float* sf = (float*)S;
    float* myin = sf + half * 2880;
    float* mywv = sf + 5760 + half * 72;
    const float* src = cf + ((size_t)b * 2 + m) * 65536;
    for (int i = t; i < 5760; i += 512) sf[i] = 0.f;
    float acc = 0.f;
    for (int it = 0; it < 16; ++it) {
      int ic0 = half * 128 + it * 8;
      __syncthreads();
#pragma unroll
      for (int i = 0; i < 8; ++i)
        myin[i * 360 + (row + 1) * 20 + (col + 1)] = src[(ic0 + i) * 256 + px];
      if (px < 72) mywv[px] = wval[2304 + ic0 * 9 + px];
      __syncthreads();
#pragma unroll
      for (int i = 0; i < 8; ++i)
#pragma unroll
        for (int ky = 0; ky < 3; ++ky)
#pragma unroll
          for (int kx = 0; kx < 3; ++kx)
            acc += myin[i * 360 + (row + ky) * 20 + (col + kx)] * mywv[i * 9 + ky * 3 + kx];
    }
    __syncthreads();
    if (half == 1) sf[5904 + px] = acc;
    __syncthreads();
    if (half == 0) sraw[(size_t)b * 768 + (1 + m) * 256 + px] = acc + sf[5904 + px];
    return;
  }

  // ---- GEMM core (enc conv or recgemm)
  const int ksplit = wave >> 2, wq = wave & 3;
  const int mw = wq >> 1, nw = wq & 1;
  const int mlane = lane & 15, quad = lane >> 4;
  const bool isConv = L < 256;

  int img = 0, b = 0, pt, ot, nkits;
  const char *Ag, *Bg;
  size_t brs;
  if (isConv) {
    int xcd = L & 7, sl = L >> 3;
    img = xcd * 8 + (sl & 7);
    int tile = sl >> 3;
    pt = tile >> 1; ot = tile & 1;
    Ag = (const char*)Xin + (size_t)img * 165888;
    Bg = (const char*)Wr;
    brs = 4608; nkits = 36;
  } else {
    int l2 = L - 256;
    b = l2 >> 2;
    int tile = l2 & 3;
    pt = tile >> 1; ot = tile & 1;
    Ag = (const char*)BmT + (size_t)b * 131072;
    Bg = (const char*)Ans + (size_t)b * 131072;
    brs = 512; nkits = 4;
  }

  int laneA[2];
#pragma unroll
  for (int r = 0; r < 2; ++r) {
    int id = r * 512 + t;
    int row = id >> 3, sub = id & 7, q = sub ^ (row & 7);
    if (isConv) {
      int p = pt * 128 + row, y = p >> 4, x = p & 15;
      laneA[r] = (y * 18 + x) * 512 + q * 16;
    } else {
      laneA[r] = (pt * 128 + row) * 512 + q * 16;
    }
  }
  int aoff[4];
#pragma unroll
  for (int i = 0; i < 4; ++i) {
    int rowm = mw * 64 + i * 16 + mlane;
    aoff[i] = rowm * 128 + (((ksplit * 4 + quad) ^ (rowm & 7)) * 16);
  }
  const char* pB[4];
#pragma unroll
  for (int n = 0; n < 4; ++n) {
    int rowb = ot * 128 + nw * 64 + n * 16 + mlane;
    pB[n] = Bg + (size_t)rowb * brs + ksplit * 64 + quad * 16;
  }

  auto stageA = [&](int kit, int buf) {
    int aG;
    if (isConv) {
      int s = kit >> 2;
      int dy = s / 3, dx = s - dy * 3;
      aG = (dy * 18 + dx) * 512 + (kit & 3) * 128;
    } else {
      aG = kit * 128;
    }
    char* dst = S + buf * 16384;
#pragma unroll
    for (int r = 0; r < 2; ++r)
      gload_lds16(Ag + laneA[r] + aG, dst + r * 8192 + wave * 1024);
  };

  f32x4 acc[4][4] = {};
  short8 bf0[4], bf1[4];
  auto loadB = [&](int kit, short8* bf) {
#pragma unroll
    for (int n = 0; n < 4; ++n) bf[n] = *(const short8*)(pB[n] + kit * 128);
  };
  auto compute = [&](int buf, short8* bf) {
    const char* Sb = S + buf * 16384;
#pragma unroll
    for (int i = 0; i < 4; ++i) {
      short8 af = *(const short8*)(Sb + aoff[i]);
#pragma unroll
      for (int n = 0; n < 4; ++n)
        acc[i][n] = __builtin_amdgcn_mfma_f32_16x16x32_bf16(af, bf[n], acc[i][n], 0, 0, 0);
    }
  };

  stageA(0, 0); loadB(0, bf0);
  for (int kit = 0; kit < nkits; kit += 2) {
    asm volatile("s_waitcnt vmcnt(0)" ::: "memory");
    asm volatile("s_barrier" ::: "memory");
    if (kit + 1 < nkits) { stageA(kit + 1, 1); loadB(kit + 1, bf1); }
    compute(0, bf0);
    asm volatile("s_waitcnt vmcnt(0)" ::: "memory");
    asm volatile("s_barrier" ::: "memory");
    if (kit + 2 < nkits) { stageA(kit + 2, 0); loadB(kit + 2, bf0); }
    compute(1, bf1);
  }

  // cross-ksplit reduction: 2 rounds through the 32KB A-buffers
  __syncthreads();
#pragma unroll
  for (int rr = 0; rr < 2; ++rr) {
    if (ksplit == 1 && (wq >> 1) == rr) {
#pragma unroll
      for (int i = 0; i < 4; ++i)
#pragma unroll
        for (int n = 0; n < 4; ++n)
          *(f32x4*)(S + (wq & 1) * 16384 + (i * 4 + n) * 1024 + lane * 16) = acc[i][n];
    }
    __syncthreads();
    if (ksplit == 0 && (wq >> 1) == rr) {
#pragma unroll
      for (int i = 0; i < 4; ++i)
#pragma unroll
        for (int n = 0; n < 4; ++n)
          acc[i][n] += *(const f32x4*)(S + (wq & 1) * 16384 + (i * 4 + n) * 1024 + lane * 16);
    }
    __syncthreads();
  }

  if (ksplit == 0) {
    unsigned short* ob = isConv ? Midp + (size_t)img * 82944 : Recp + (size_t)b * 82944;
#pragma unroll
    for (int i = 0; i < 4; ++i) {
      int m0 = pt * 128 + mw * 64 + i * 16 + quad * 4;
#pragma unroll
      for (int n = 0; n < 4; ++n) {
        int oc = ot * 128 + nw * 64 + n * 16 + mlane;
        float bv = isConv ? bias[oc] : 0.f;
#pragma unroll
        for (int r = 0; r < 4; ++r) {
          int p = m0 + r;
          int y = p >> 4, x = p & 15;
          float v = acc[i][n][r] + bv;
          if (isConv) v = fmaxf(v, 0.f);
          ob[(size_t)(y * 18 + x + 19) * 256 + oc] = f2bf(v);
        }
      }
    }
  }
}

// dec merged: units 0..63 = dec(Midp)+loss vs cf; 64..95 = dec(Recp)->rec2+minmax
__global__ __launch_bounds__(512, 4) void conv_dec_k(
    const unsigned short* __restrict__ Midp, const unsigned short* __restrict__ Recp,
    const unsigned short* __restrict__ Wr, const float* __restrict__ bias,
    const float* __restrict__ cfref, float* __restrict__ rec2,
    float* __restrict__ lacc, unsigned* __restrict__ mm) {
  __shared__ __align__(16) char S[32768];
  __shared__ float sred[4], smn[4], smx[4];
  const int t = threadIdx.x, lane = t & 63, wave = t >> 6;
  const int ksplit = wave >> 2, wq = wave & 3;
  const int mw = wq >> 1, nw = wq & 1;
  const int mlane = lane & 15, quad = lane >> 4;
  const int L = blockIdx.x;
  const int xcd = L & 7, sl = L >> 3;
  const int u12 = sl % 12, tile = sl / 12;
  const int unit = xcd * 12 + u12;
  const bool isLoss = unit < 64;
  const int pt = tile >> 1, ot = tile & 1;

  int laneA[2];
#pragma unroll
  for (int r = 0; r < 2; ++r) {
    int id = r * 512 + t;
    int row = id >> 3, sub = id & 7, q = sub ^ (row & 7);
    int p = pt * 128 + row, y = p >> 4, x = p & 15;
    laneA[r] = (y * 18 + x) * 512 + q * 16;
  }
  const char* Ag = isLoss ? (const char*)Midp + (size_t)unit * 165888
                          : (const char*)Recp + (size_t)(unit - 64) * 165888;
  const char* Bg = (const char*)Wr;

  int aoff[4];
#pragma unroll
  for (int i = 0; i < 4; ++i) {
    int rowm = mw * 64 + i * 16 + mlane;
    aoff[i] = rowm * 128 + (((ksplit * 4 + quad) ^ (rowm & 7)) * 16);
  }
  const char* pB[4];
#pragma unroll
  for (int n = 0; n < 4; ++n) {
    int rowb = ot * 128 + nw * 64 + n * 16 + mlane;
    pB[n] = Bg + (size_t)rowb * 4608 + ksplit * 64 + quad * 16;
  }

  auto stageA = [&](int kit, int buf) {
    int s = kit >> 2;
    int dy = s / 3, dx = s - dy * 3;
    int aG = (dy * 18 + dx) * 512 + (kit & 3) * 128;
    char* dst = S + buf * 16384;
#pragma unroll
    for (int r = 0; r < 2; ++r)
      gload_lds16(Ag + laneA[r] + aG, dst + r * 8192 + wave * 1024);
  };

  f32x4 acc[4][4] = {};
  short8 bf0[4], bf1[4];
  auto loadB = [&](int kit, short8* bf) {
#pragma unroll
    for (int n = 0; n < 4; ++n) bf[n] = *(const short8*)(pB[n] + kit * 128);
  };
  auto compute = [&](int buf, short8* bf) {
    const char* Sb = S + buf * 16384;
#pragma unroll
    for (int i = 0; i < 4; ++i) {
      short8 af = *(const short8*)(Sb + aoff[i]);
#pragma unroll
      for (int n = 0; n < 4; ++n)
        acc[i][n] = __builtin_amdgcn_mfma_f32_16x16x32_bf16(af, bf[n], acc[i][n], 0, 0, 0);
    }
  };

  stageA(0, 0); loadB(0, bf0);
  for (int kit = 0; kit < 36; kit += 2) {
    asm volatile("s_waitcnt vmcnt(0)" ::: "memory");
    asm volatile("s_barrier" ::: "memory");
    if (kit + 1 < 36) { stageA(kit + 1, 1); loadB(kit + 1, bf1); }
    compute(0, bf0);
    asm volatile("s_waitcnt vmcnt(0)" ::: "memory");
    asm volatile("s_barrier" ::: "memory");
    if (kit + 2 < 36) { stageA(kit + 2, 0); loadB(kit + 2, bf0); }
    compute(1, bf1);
  }

  __syncthreads();
#pragma unroll
  for (int rr = 0; rr < 2; ++rr) {
    if (ksplit == 1 && (wq >> 1) == rr) {
#pragma unroll
      for (int i = 0; i < 4; ++i)
#pragma unroll
        for (int n = 0; n < 4; ++n)
          *(f32x4*)(S + (wq & 1) * 16384 + (i * 4 + n) * 1024 + lane * 16) = acc[i][n];
    }
    __syncthreads();
    if (ksplit == 0 && (wq >> 1) == rr) {
#pragma unroll
      for (int i = 0; i < 4; ++i)
#pragma unroll
        for (int n = 0; n < 4; ++n)
          acc[i][n] += *(const f32x4*)(S + (wq & 1) * 16384 + (i * 4 + n) * 1024 + lane * 16);
    }
    __syncthreads();
  }

  if (ksplit == 0) {
    if (isLoss) {
      float ls = 0.f;
#pragma unroll
      for (int i = 0; i < 4; ++i) {
        int m0 = pt * 128 + mw * 64 + i * 16 + quad * 4;
#pragma unroll
        for (int n = 0; n < 4; ++n) {
          int oc = ot * 128 + nw * 64 + n * 16 + mlane;
          float bv = bias[oc];
          float4 c4 = *(const float4*)(cfref + (size_t)unit * 65536 + (size_t)oc * 256 + m0);
          float d0 = acc[i][n][0] + bv - c4.x;
          float d1 = acc[i][n][1] + bv - c4.y;
          float d2 = acc[i][n][2] + bv - c4.z;
          float d3 = acc[i][n][3] + bv - c4.w;
          ls += d0 * d0 + d1 * d1 + d2 * d2 + d3 * d3;
        }
      }
#pragma unroll
      for (int off = 32; off; off >>= 1) ls += __shfl_down(ls, off);
      if (lane == 0) sred[wq] = ls;
    } else {
      const int img2 = unit - 64;
      float mn = INFINITY, mx = -INFINITY;
#pragma unroll
      for (int i = 0; i < 4; ++i) {
        int m0 = pt * 128 + mw * 64 + i * 16 + quad * 4;
#pragma unroll
        for (int n = 0; n < 4; ++n) {
          int oc = ot * 128 + nw * 64 + n * 16 + mlane;
          float bv = bias[oc];
          float4 v;
          v.x = acc[i][n][0] + bv; v.y = acc[i][n][1] + bv;
          v.z = acc[i][n][2] + bv; v.w = acc[i][n][3] + bv;
          mn = fminf(mn, fminf(fminf(v.x, v.y), fminf(v.z, v.w)));
          mx = fmaxf(mx, fmaxf(fmaxf(v.x, v.y), fmaxf(v.z, v.w)));
          *(float4*)(rec2 + (size_t)img2 * 65536 + (size_t)oc * 256 + m0) = v;
        }
      }
#pragma unroll
      for (int off = 32; off; off >>= 1) {
        mn = fminf(mn, __shfl_down(mn, off));
        mx = fmaxf(mx, __shfl_down(mx, off));
      }
      if (lane == 0) { smn[wq] = mn; smx[wq] = mx; }
    }
  }
  __syncthreads();
  if (t == 0) {
    if (isLoss) {
      atomicAdd(lacc, sred[0] + sred[1] + sred[2] + sred[3]);
    } else {
      float a = fminf(fminf(smn[0], smn[1]), fminf(smn[2], smn[3]));
      float b2 = fmaxf(fmaxf(smx[0], smx[1]), fmaxf(smx[2], smx[3]));
      atomicMin(&mm[0], mapf(a));
      atomicMax(&mm[1], mapf(b2));
    }
  }
}

// score on RAW rec2 (normalization folded into fuse): 32 blocks x 512
__global__ __launch_bounds__(512) void score_rec_k(
    const float* __restrict__ rec2, const float* __restrict__ wval,
    float* __restrict__ sraw) {
  __shared__ float sf[6160];
  const int b = blockIdx.x, t = threadIdx.x;
  const int half = t >> 8, px = t & 255;
  const int row = px >> 4, col = px & 15;
  float* myin = sf + half * 2880;
  float* mywv = sf + 5760 + half * 72;
  const float* src = rec2 + (size_t)b * 65536;
  for (int i = t; i < 5760; i += 512) sf[i] = 0.f;
  float acc = 0.f;
  for (int it = 0; it < 16; ++it) {
    int ic0 = half * 128 + it * 8;
    __syncthreads();
#pragma unroll
    for (int i = 0; i < 8; ++i)
      myin[i * 360 + (row + 1) * 20 + (col + 1)] = src[(ic0 + i) * 256 + px];
    if (px < 72) mywv[px] = wval[ic0 * 9 + px];
    __syncthreads();
#pragma unroll
    for (int i = 0; i < 8; ++i)
#pragma unroll
      for (int ky = 0; ky < 3; ++ky)
#pragma unroll
        for (int kx = 0; kx < 3; ++kx)
          acc += myin[i * 360 + (row + ky) * 20 + (col + kx)] * mywv[i * 9 + ky * 3 + kx];
  }
  __syncthreads();
  if (half == 1) sf[5904 + px] = acc;
  __syncthreads();
  if (half == 0) sraw[(size_t)b * 768 + px] = acc + sf[5904 + px];
}

__global__ void fuse_k(const float* __restrict__ cf, const float* __restrict__ rec2,
                       const float* __restrict__ sraw, const float* __restrict__ bval,
                       const unsigned* __restrict__ mm, const float* __restrict__ lacc,
                       const float* __restrict__ wsum9, float* __restrict__ outp) {
  const int idx = blockIdx.x * 256 + threadIdx.x;
  const int b = idx >> 16;
  const int rest = idx & 65535;
  const int pos = idx & 255;
  const float mn = unmapf(mm[0]), mx = unmapf(mm[1]);
  const float sc = 2.f / (mx - mn), sh = -mn * sc - 1.f;
  // de-normalized rec-score: conv(sc*rec+sh) = sc*conv(rec) + sh*P(pos)
  const int y = pos >> 4, x = pos & 15;
  float P = 0.f;
#pragma unroll
  for (int ky = 0; ky < 3; ++ky) {
    int yy = y + ky - 1;
    if (yy < 0 || yy > 15) continue;
#pragma unroll
    for (int kx = 0; kx < 3; ++kx) {
      int xx = x + kx - 1;
      if (xx < 0 || xx > 15) continue;
      P += wsum9[ky * 3 + kx];
    }
  }
  const float srec = sc * sraw[(size_t)b * 768 + pos] + sh * P;
  const float sc0 = sraw[(size_t)b * 768 + 256 + pos];
  const float sc1 = sraw[(size_t)b * 768 + 512 + pos];
  const float bv = bval[0];
  const float z0 = fmaxf(srec + sc0 + bv, 0.f);
  const float z1 = fmaxf(srec + sc1 + bv, 0.f);
  const float s0 = 1.f / (1.f + expf(-z0));
  const float s1 = 1.f / (1.f + expf(-z1));
  const float w0 = 1.f / (1.f + expf(s1 - s0));
  const float w1 = 1.f - w0;
  const float rn = fmaf(rec2[idx], sc, sh);
  const float f0 = cf[(size_t)b * 131072 + rest];
  const float f1 = cf[(size_t)b * 131072 + 65536 + rest];
  outp[idx] = 0.2f * (w0 * f0 + w1 * f1) + 0.8f * rn;
  if (idx == 0) outp[2097152] = lacc[0] * (1.f / 4194304.f);
}

extern "C" void kernel_launch(void* const* d_in, const int* in_sizes, int n_in,
                              void* d_out, int out_size, void* d_ws, size_t ws_size,
                              hipStream_t stream) {
  const float* cf    = (const float*)d_in[0];
  const float* fs    = (const float*)d_in[1];
  const float* fv    = (const float*)d_in[2];
  const float* fd    = (const float*)d_in[3];
  const float* w_enc = (const float*)d_in[4];
  const float* b_enc = (const float*)d_in[5];
  const float* w_dec = (const float*)d_in[6];
  const float* b_dec = (const float*)d_in[7];
  const float* w_val = (const float*)d_in[8];
  const float* b_val = (const float*)d_in[9];
  float* out = (float*)d_out;
  float* wsf = (float*)d_ws;

  // ws layout (float offsets); Xp and Midp must stay contiguous (halo blocks).
  unsigned short* Xp   = (unsigned short*)wsf;                  // 64 img padded NHWC
  unsigned short* Midp = (unsigned short*)(wsf + 2654208);      // 64 img
  unsigned short* Recp = (unsigned short*)(wsf + 5308416);      // 32 img
  float* rec2 = wsf + 6635520;                                  // 2,097,152 NCHW f32
  unsigned short* WrE = (unsigned short*)(wsf + 8732672);
  unsigned short* WrD = (unsigned short*)(wsf + 9027584);
  unsigned short* Ans = (unsigned short*)(wsf + 9322496);
  unsigned short* BmT = (unsigned short*)(wsf + 10371072);
  float* sraw = wsf + 11419648;                                 // 24,576
  float* wsum9 = wsf + 11444224;                                // 9
  float* lacc = wsf + 11444240;
  unsigned* mm = (unsigned*)(wsf + 11444241);

  prep_k<<<3937, 256, 0, stream>>>(cf, w_enc, w_dec, fv, fs, fd, w_val,
                                   Xp, WrE, WrD, Ans, BmT, Recp, wsum9, lacc, mm);
  encrec_k<<<448, 512, 0, stream>>>(Xp, WrE, b_enc, Midp, BmT, Ans, Recp,
                                    cf, w_val, sraw);
  conv_dec_k<<<384, 512, 0, stream>>>(Midp, Recp, WrD, b_dec, cf, rec2, lacc, mm);
  score_rec_k<<<32, 512, 0, stream>>>(rec2, w_val, sraw);
  fuse_k<<<8192, 256, 0, stream>>>(cf, rec2, sraw, b_val, mm, lacc, wsum9, out);
}

// Round 10
// 253.544 us; speedup vs baseline: 1.2328x; 1.2328x over previous
//
#include <hip/hip_runtime.h>
#include <math.h>

// Shapes (fixed): B=32, M=2, C=256, H=W=16, N=256, DIM=256, THR=0.1, RATIO=0.8
// out: fused (32,256,16,16) = 2,097,152 floats, then auto_enc_loss (1 float)
//
// R10 = R8's proven GEMM core (LDS-staged A+B via global_load_lds, 128x128
// tile, BK=64, ksplit wave tiling, 2x32KB buffers) + R9's launch structure
// (5 launches: mega-prep w/ folded ansbmt, encrec w/ score_cf blocks,
// merged dec, de-normalized score_rec, fuse). R9's B-direct-to-register
// regressed 2x (scattered 64B segments; request-rate bound) -- reverted.

typedef __attribute__((ext_vector_type(8))) short short8;
typedef __attribute__((ext_vector_type(4))) float f32x4;

__device__ __forceinline__ void gload_lds16(const void* g, void* l) {
  __builtin_amdgcn_global_load_lds(
      (const __attribute__((address_space(1))) void*)g,
      (__attribute__((address_space(3))) void*)l, 16, 0, 0);
}

__device__ __forceinline__ unsigned short f2bf(float f) {
  unsigned u = __float_as_uint(f);
  unsigned r = (u + 0x7FFFu + ((u >> 16) & 1u)) >> 16;  // RNE
  return (unsigned short)r;
}

__device__ __forceinline__ unsigned mapf(float f) {
  unsigned u = __float_as_uint(f);
  return (u & 0x80000000u) ? ~u : (u | 0x80000000u);
}
__device__ __forceinline__ float unmapf(unsigned u) {
  unsigned v = (u & 0x80000000u) ? (u & 0x7fffffffu) : ~u;
  return __uint_as_float(v);
}

// closed-form slot counts for batch b (same arithmetic as reference)
__device__ __forceinline__ void slot_counts(const float* __restrict__ fv, int b,
                                            int t, int* shm, int& c0o, int& c1o) {
  const float v0 = fv[(size_t)b * 512 + t];
  const float v1 = fv[(size_t)b * 512 + 256 + t];
  const unsigned long long bal0 = __ballot(v0 > 0.1f);
  const unsigned long long bal1 = __ballot(v1 > 0.1f);
  const int wid = t >> 6, lane = t & 63;
  if (lane == 0) { shm[wid] = __popcll(bal0); shm[4 + wid] = __popcll(bal1); }
  __syncthreads();
  int c0 = shm[0] + shm[1] + shm[2] + shm[3];
  int c1 = shm[4] + shm[5] + shm[6] + shm[7];
  int total = c0 + c1;
  if (total > 256) {
    int a0 = (int)rintf(256.0f * (float)c0 / (float)total);
    c0 = a0; c1 = 256 - a0;
  }
  c0o = max(c0, 0); c1o = max(c1, 0);
}

// ---------------- mega-prep: pack | wrk | halos | ansb | bmt | wsum9+init
__global__ __launch_bounds__(256) void prep_k(
    const float* __restrict__ cf, const float* __restrict__ we,
    const float* __restrict__ wd, const float* __restrict__ fv,
    const float* __restrict__ fs, const float* __restrict__ fd,
    const float* __restrict__ wval,
    unsigned short* __restrict__ Xp, unsigned short* __restrict__ WrE,
    unsigned short* __restrict__ WrD, unsigned short* __restrict__ Ans,
    unsigned short* __restrict__ BmT, unsigned short* __restrict__ Recp,
    float* __restrict__ wsum9, float* __restrict__ lacc,
    unsigned* __restrict__ mm) {
  __shared__ float sIn[4096];
  __shared__ int shm[8];
  const int bx = blockIdx.x, t = threadIdx.x;
  if (bx < 2048) {                       // pack: cf NCHW f32 -> padded NHWC bf16
    int idx = bx * 256 + t;
    int p = idx & 255, ch = (idx >> 8) & 31, img = idx >> 13;
    int ic0 = ch * 8;
    const float* sp = cf + (size_t)img * 65536 + (size_t)ic0 * 256 + p;
    unsigned short h[8];
#pragma unroll
    for (int i = 0; i < 8; ++i) h[i] = f2bf(sp[i * 256]);
    int y = p >> 4, x = p & 15;
    uint4 u;
    u.x = h[0] | (h[1] << 16); u.y = h[2] | (h[3] << 16);
    u.z = h[4] | (h[5] << 16); u.w = h[6] | (h[7] << 16);
    *(uint4*)&Xp[(size_t)img * 82944 + (size_t)(y * 18 + x + 19) * 256 + ic0] = u;
  } else if (bx < 2624) {                // wrk: OIHW f32 -> Wr[oc][s][ic] bf16
    int idx = (bx - 2048) * 256 + t;
    int ch = idx & 31, rest = idx >> 5;
    int s = rest % 9, ocx = rest / 9;
    int oc = ocx & 255, cv = ocx >> 8;
    const float* w = cv ? wd : we;
    unsigned short* o = cv ? WrD : WrE;
    int ic0 = ch * 8;
    unsigned short h[8];
#pragma unroll
    for (int i = 0; i < 8; ++i) h[i] = f2bf(w[(size_t)oc * 2304 + (ic0 + i) * 9 + s]);
    uint4 u;
    u.x = h[0] | (h[1] << 16); u.y = h[2] | (h[3] << 16);
    u.z = h[4] | (h[5] << 16); u.w = h[6] | (h[7] << 16);
    *(uint4*)&o[(size_t)oc * 2304 + s * 256 + ic0] = u;
  } else if (bx < 2752) {                // halo zero: Xp 0..63 | Midp (contig) 64..127
    int img = bx - 2624;
    uint4* base = (uint4*)Xp + (size_t)img * 10368;
    uint4 z; z.x = z.y = z.z = z.w = 0;
    for (int it = t; it < 2176; it += 256) {
      int px = it >> 5, c = it & 31;
      int y, x;
      if (px < 18)      { y = 0;  x = px; }
      else if (px < 36) { y = 17; x = px - 18; }
      else if (px < 52) { y = px - 35; x = 0; }
      else              { y = px - 51; x = 17; }
      base[(y * 18 + x) * 32 + c] = z;
    }
  } else if (bx < 2784) {                // Recp halo zero (32 imgs)
    int img = bx - 2752;
    uint4* base = (uint4*)Recp + (size_t)img * 10368;
    uint4 z; z.x = z.y = z.z = z.w = 0;
    for (int it = t; it < 2176; it += 256) {
      int px = it >> 5, c = it & 31;
      int y, x;
      if (px < 18)      { y = 0;  x = px; }
      else if (px < 36) { y = 17; x = px - 18; }
      else if (px < 52) { y = px - 35; x = 0; }
      else              { y = px - 51; x = 17; }
      base[(y * 18 + x) * 32 + c] = z;
    }
  } else if (bx < 3808) {                // ansb: Ans[b][c][j] = ns[c][j]*v_j
    int bi = bx - 2784;
    int b = bi >> 5, cbase = (bi & 31) * 8;
    int c0, c1;
    slot_counts(fv, b, t, shm, c0, c1);
    int c = cbase + (t >> 5), ch = t & 31, j0 = ch * 8;
    int m = -1, r = 0;
    if (c < c0) { m = 0; r = c; }
    else if (c - c0 < c1) { m = 1; r = c - c0; }
    unsigned short h[8] = {0, 0, 0, 0, 0, 0, 0, 0};
    if (m >= 0) {
      const float* fp = fs + (((size_t)b * 2 + m) * 256 + r) * 256 + j0;
#pragma unroll
      for (int i = 0; i < 8; ++i) {
        int j = j0 + i;
        float vj = 0.f;
        if (j < c0) vj = fv[(size_t)b * 512 + j];
        else if (j - c0 < c1) vj = fv[(size_t)b * 512 + 256 + (j - c0)];
        h[i] = f2bf(fp[i] * vj);
      }
    }
    uint4 u;
    u.x = h[0] | (h[1] << 16); u.y = h[2] | (h[3] << 16);
    u.z = h[4] | (h[5] << 16); u.w = h[6] | (h[7] << 16);
    *(uint4*)&Ans[(size_t)b * 65536 + c * 256 + j0] = u;
  } else if (bx < 3936) {                // bmt: BmT[b][p][j] = fd[b,m_p,j,r_p]
    int bi = bx - 3808;
    int b = bi >> 2, bz = bi & 3;
    int c0, c1;
    slot_counts(fv, b, t, shm, c0, c1);
    int m_p = -1, r_p = 0;
    if (t < c0) { m_p = 0; r_p = t; }
    else if (t - c0 < c1) { m_p = 1; r_p = t - c0; }
    for (int jg = bz * 8; jg < bz * 8 + 8; ++jg) {
      __syncthreads();
#pragma unroll
      for (int u = 0; u < 4; ++u) {
        int q = t * 4 + u;
        int rr = q >> 6, w = q & 63;
        int m = rr >> 3, i = rr & 7;
        float4 f = ((const float4*)fd)[((size_t)(b * 2 + m) * 256 + jg * 8 + i) * 64 + w];
        *(float4*)&sIn[i * 512 + m * 256 + w * 4] = f;
      }
      __syncthreads();
      unsigned short h[8] = {0, 0, 0, 0, 0, 0, 0, 0};
      if (m_p >= 0) {
#pragma unroll
        for (int i = 0; i < 8; ++i) h[i] = f2bf(sIn[i * 512 + m_p * 256 + r_p]);
      }
      uint4 u;
      u.x = h[0] | (h[1] << 16); u.y = h[2] | (h[3] << 16);
      u.z = h[4] | (h[5] << 16); u.w = h[6] | (h[7] << 16);
      *(uint4*)&BmT[(size_t)b * 65536 + t * 256 + jg * 8] = u;
    }
  } else {                               // wsum9 + init
    for (int j = 0; j < 9; ++j) {
      float v = wval[t * 9 + j];
#pragma unroll
      for (int off = 32; off; off >>= 1) v += __shfl_down(v, off);
      if ((t & 63) == 0) sIn[t >> 6] = v;
      __syncthreads();
      if (t == 0) wsum9[j] = sIn[0] + sIn[1] + sIn[2] + sIn[3];
      __syncthreads();
    }
    if (t == 0) { lacc[0] = 0.f; mm[0] = 0xFFFFFFFFu; mm[1] = 0u; }
  }
}

// ======= encrec: [0,256) enc conv | [256,384) recgemm | [384,448) score_cf
// GEMM core: 128x128, BK=64, 512 thr; LDS 2x32KB (A [0,16K), B [16K,32K));
// ksplit wave tiling (8 reads -> 16 MFMA); one-round ksplit reduction in S.
__global__ __launch_bounds__(512, 4) void encrec_k(
    const unsigned short* __restrict__ Xin, const unsigned short* __restrict__ Wr,
    const float* __restrict__ bias, unsigned short* __restrict__ Midp,
    const unsigned short* __restrict__ BmT, const unsigned short* __restrict__ Ans,
    unsigned short* __restrict__ Recp, const float* __restrict__ cf,
    const float* __restrict__ wval, float* __restrict__ sraw) {
  __shared__ __align__(16) char S[65536];
  const int t = threadIdx.x, lane = t & 63, wave = t >> 6;
  const int L = blockIdx.x;

  if (L >= 384) {                        // ---- score_cf: (b, m) 1-ch conv on cf
    const int sb = L - 384;
    const int b = sb >> 1, m = sb & 1;
    const int half = t >> 8, px = t & 255;
    const int row = px >> 4, col = px & 15;
    float* sf = (float*)S;
    float* myin = sf + half * 2880;
    float* mywv = sf + 5760 + half * 72;
    const float* src = cf + ((size_t)b * 2 + m) * 65536;
    for (int i = t; i < 5760; i += 512) sf[i] = 0.f;
    float acc = 0.f;
    for (int it = 0; it < 16; ++it) {
      int ic0 = half * 128 + it * 8;
      __syncthreads();
#pragma unroll
      for (int i = 0; i < 8; ++i)
        myin[i * 360 + (row + 1) * 20 + (col + 1)] = src[(ic0 + i) * 256 + px];
      if (px < 72) mywv[px] = wval[2304 + ic0 * 9 + px];
      __syncthreads();
#pragma unroll
      for (int i = 0; i < 8; ++i)
#pragma unroll
        for (int ky = 0; ky < 3; ++ky)
#pragma unroll
          for (int kx = 0; kx < 3; ++kx)
            acc += myin[i * 360 + (row + ky) * 20 + (col + kx)] * mywv[i * 9 + ky * 3 + kx];
    }
    __syncthreads();
    if (half == 1) sf[5904 + px] = acc;
    __syncthreads();
    if (half == 0) sraw[(size_t)b * 768 + (1 + m) * 256 + px] = acc + sf[5904 + px];
    return;
  }

  // ---- GEMM core (enc conv or recgemm)
  const int ksplit = wave >> 2, wq = wave & 3;
  const int mw = wq >> 1, nw = wq & 1;
  const int mlane = lane & 15, quad = lane >> 4;
  const bool isConv = L < 256;

  int img = 0, b = 0, pt, ot, nkits;
  const char *Ag, *Bg;
  int laneA[2], laneB[2];
  if (isConv) {
    int xcd = L & 7, sl = L >> 3;
    img = xcd * 8 + (sl & 7);
    int tile = sl >> 3;
    pt = tile >> 1; ot = tile & 1;
    Ag = (const char*)Xin + (size_t)img * 165888;
    Bg = (const char*)Wr;
#pragma unroll
    for (int r = 0; r < 2; ++r) {
      int id = r * 512 + t;
      int row = id >> 3, sub = id & 7, q = sub ^ (row & 7);
      int p = pt * 128 + row, y = p >> 4, x = p & 15;
      laneA[r] = (y * 18 + x) * 512 + q * 16;
      laneB[r] = (ot * 128 + row) * 4608 + q * 16;
    }
    nkits = 36;
  } else {
    int l2 = L - 256;
    b = l2 >> 2;
    int tile = l2 & 3;
    pt = tile >> 1; ot = tile & 1;
    Ag = (const char*)BmT + (size_t)b * 131072;
    Bg = (const char*)Ans + (size_t)b * 131072;
#pragma unroll
    for (int r = 0; r < 2; ++r) {
      int id = r * 512 + t;
      int row = id >> 3, sub = id & 7, q = sub ^ (row & 7);
      laneA[r] = (pt * 128 + row) * 512 + q * 16;
      laneB[r] = (ot * 128 + row) * 512 + q * 16;
    }
    nkits = 4;
  }

  int aoff[4], boff[4];
#pragma unroll
  for (int i = 0; i < 4; ++i) {
    int rowm = mw * 64 + i * 16 + mlane;
    aoff[i] = rowm * 128 + (((ksplit * 4 + quad) ^ (rowm & 7)) * 16);
    int rown = nw * 64 + i * 16 + mlane;
    boff[i] = 16384 + rown * 128 + (((ksplit * 4 + quad) ^ (rown & 7)) * 16);
  }

  auto stage = [&](int kit, int buf) {
    int aG, bG = kit * 128;
    if (isConv) {
      int s = kit >> 2;
      int dy = s / 3, dx = s - dy * 3;
      aG = (dy * 18 + dx) * 512 + (kit & 3) * 128;
    } else {
      aG = kit * 128;
    }
    char* dst = S + buf * 32768;
#pragma unroll
    for (int r = 0; r < 2; ++r)
      gload_lds16(Ag + laneA[r] + aG, dst + r * 8192 + wave * 1024);
#pragma unroll
    for (int r = 0; r < 2; ++r)
      gload_lds16(Bg + laneB[r] + bG, dst + 16384 + r * 8192 + wave * 1024);
  };

  f32x4 acc[4][4] = {};
  stage(0, 0);
  for (int kit = 0; kit < nkits; ++kit) {
    int cur = kit & 1;
    asm volatile("s_waitcnt vmcnt(0)" ::: "memory");
    asm volatile("s_barrier" ::: "memory");
    if (kit + 1 < nkits) stage(kit + 1, 1 - cur);
    const char* Sb = S + cur * 32768;
    short8 af[4], bf[4];
#pragma unroll
    for (int i = 0; i < 4; ++i) {
      af[i] = *(const short8*)(Sb + aoff[i]);
      bf[i] = *(const short8*)(Sb + boff[i]);
    }
#pragma unroll
    for (int i = 0; i < 4; ++i)
#pragma unroll
      for (int n = 0; n < 4; ++n)
        acc[i][n] = __builtin_amdgcn_mfma_f32_16x16x32_bf16(af[i], bf[n], acc[i][n], 0, 0, 0);
  }

  // cross-ksplit reduction through LDS (one round, 64KB)
  __syncthreads();
  if (ksplit == 1) {
#pragma unroll
    for (int i = 0; i < 4; ++i)
#pragma unroll
      for (int n = 0; n < 4; ++n)
        *(f32x4*)(S + wq * 16384 + (i * 4 + n) * 1024 + lane * 16) = acc[i][n];
  }
  __syncthreads();
  if (ksplit == 0) {
#pragma unroll
    for (int i = 0; i < 4; ++i)
#pragma unroll
      for (int n = 0; n < 4; ++n)
        acc[i][n] += *(const f32x4*)(S + wq * 16384 + (i * 4 + n) * 1024 + lane * 16);
    unsigned short* ob = isConv ? Midp + (size_t)img * 82944 : Recp + (size_t)b * 82944;
#pragma unroll
    for (int i = 0; i < 4; ++i) {
      int m0 = pt * 128 + mw * 64 + i * 16 + quad * 4;
#pragma unroll
      for (int n = 0; n < 4; ++n) {
        int oc = ot * 128 + nw * 64 + n * 16 + mlane;
        float bv = isConv ? bias[oc] : 0.f;
#pragma unroll
        for (int r = 0; r < 4; ++r) {
          int p = m0 + r;
          int y = p >> 4, x = p & 15;
          float v = acc[i][n][r] + bv;
          if (isConv) v = fmaxf(v, 0.f);
          ob[(size_t)(y * 18 + x + 19) * 256 + oc] = f2bf(v);
        }
      }
    }
  }
}

// dec merged: units 0..63 = dec(Midp)+loss vs cf; 64..95 = dec(Recp)->rec2+minmax
__global__ __launch_bounds__(512, 4) void conv_dec_k(
    const unsigned short* __restrict__ Midp, const unsigned short* __restrict__ Recp,
    const unsigned short* __restrict__ Wr, const float* __restrict__ bias,
    const float* __restrict__ cfref, float* __restrict__ rec2,
    float* __restrict__ lacc, unsigned* __restrict__ mm) {
  __shared__ __align__(16) char S[65536];
  __shared__ float sred[4], smn[4], smx[4];
  const int t = threadIdx.x, lane = t & 63, wave = t >> 6;
  const int ksplit = wave >> 2, wq = wave & 3;
  const int mw = wq >> 1, nw = wq & 1;
  const int mlane = lane & 15, quad = lane >> 4;
  const int L = blockIdx.x;
  const int xcd = L & 7, sl = L >> 3;
  const int u12 = sl % 12, tile = sl / 12;
  const int unit = xcd * 12 + u12;
  const bool isLoss = unit < 64;
  const int pt = tile >> 1, ot = tile & 1;

  int laneA[2], laneB[2];
#pragma unroll
  for (int r = 0; r < 2; ++r) {
    int id = r * 512 + t;
    int row = id >> 3, sub = id & 7, q = sub ^ (row & 7);
    int p = pt * 128 + row, y = p >> 4, x = p & 15;
    laneA[r] = (y * 18 + x) * 512 + q * 16;
    laneB[r] = (ot * 128 + row) * 4608 + q * 16;
  }
  const char* Ag = isLoss ? (const char*)Midp + (size_t)unit * 165888
                          : (const char*)Recp + (size_t)(unit - 64) * 165888;
  const char* Bg = (const char*)Wr;

  int aoff[4], boff[4];
#pragma unroll
  for (int i = 0; i < 4; ++i) {
    int rowm = mw * 64 + i * 16 + mlane;
    aoff[i] = rowm * 128 + (((ksplit * 4 + quad) ^ (rowm & 7)) * 16);
    int rown = nw * 64 + i * 16 + mlane;
    boff[i] = 16384 + rown * 128 + (((ksplit * 4 + quad) ^ (rown & 7)) * 16);
  }

  auto stage = [&](int kit, int buf) {
    int s = kit >> 2;
    int dy = s / 3, dx = s - dy * 3;
    int aG = (dy * 18 + dx) * 512 + (kit & 3) * 128;
    int bG = kit * 128;
    char* dst = S + buf * 32768;
#pragma unroll
    for (int r = 0; r < 2; ++r)
      gload_lds16(Ag + laneA[r] + aG, dst + r * 8192 + wave * 1024);
#pragma unroll
    for (int r = 0; r < 2; ++r)
      gload_lds16(Bg + laneB[r] + bG, dst + 16384 + r * 8192 + wave * 1024);
  };

  f32x4 acc[4][4] = {};
  stage(0, 0);
  for (int kit = 0; kit < 36; ++kit) {
    int cur = kit & 1;
    asm volatile("s_waitcnt vmcnt(0)" ::: "memory");
    asm volatile("s_barrier" ::: "memory");
    if (kit + 1 < 36) stage(kit + 1, 1 - cur);
    const char* Sb = S + cur * 32768;
    short8 af[4], bf[4];
#pragma unroll
    for (int i = 0; i < 4; ++i) {
      af[i] = *(const short8*)(Sb + aoff[i]);
      bf[i] = *(const short8*)(Sb + boff[i]);
    }
#pragma unroll
    for (int i = 0; i < 4; ++i)
#pragma unroll
      for (int n = 0; n < 4; ++n)
        acc[i][n] = __builtin_amdgcn_mfma_f32_16x16x32_bf16(af[i], bf[n], acc[i][n], 0, 0, 0);
  }

  __syncthreads();
  if (ksplit == 1) {
#pragma unroll
    for (int i = 0; i < 4; ++i)
#pragma unroll
      for (int n = 0; n < 4; ++n)
        *(f32x4*)(S + wq * 16384 + (i * 4 + n) * 1024 + lane * 16) = acc[i][n];
  }
  __syncthreads();
  if (ksplit == 0) {
#pragma unroll
    for (int i = 0; i < 4; ++i)
#pragma unroll
      for (int n = 0; n < 4; ++n)
        acc[i][n] += *(const f32x4*)(S + wq * 16384 + (i * 4 + n) * 1024 + lane * 16);

    if (isLoss) {
      float ls = 0.f;
#pragma unroll
      for (int i = 0; i < 4; ++i) {
        int m0 = pt * 128 + mw * 64 + i * 16 + quad * 4;
#pragma unroll
        for (int n = 0; n < 4; ++n) {
          int oc = ot * 128 + nw * 64 + n * 16 + mlane;
          float bv = bias[oc];
          float4 c4 = *(const float4*)(cfref + (size_t)unit * 65536 + (size_t)oc * 256 + m0);
          float d0 = acc[i][n][0] + bv - c4.x;
          float d1 = acc[i][n][1] + bv - c4.y;
          float d2 = acc[i][n][2] + bv - c4.z;
          float d3 = acc[i][n][3] + bv - c4.w;
          ls += d0 * d0 + d1 * d1 + d2 * d2 + d3 * d3;
        }
      }
#pragma unroll
      for (int off = 32; off; off >>= 1) ls += __shfl_down(ls, off);
      if (lane == 0) sred[wq] = ls;
    } else {
      const int img2 = unit - 64;
      float mn = INFINITY, mx = -INFINITY;
#pragma unroll
      for (int i = 0; i < 4; ++i) {
        int m0 = pt * 128 + mw * 64 + i * 16 + quad * 4;
#pragma unroll
        for (int n = 0; n < 4; ++n) {
          int oc = ot * 128 + nw * 64 + n * 16 + mlane;
          float bv = bias[oc];
          float4 v;
          v.x = acc[i][n][0] + bv; v.y = acc[i][n][1] + bv;
          v.z = acc[i][n][2] + bv; v.w = acc[i][n][3] + bv;
          mn = fminf(mn, fminf(fminf(v.x, v.y), fminf(v.z, v.w)));
          mx = fmaxf(mx, fmaxf(fmaxf(v.x, v.y), fmaxf(v.z, v.w)));
          *(float4*)(rec2 + (size_t)img2 * 65536 + (size_t)oc * 256 + m0) = v;
        }
      }
#pragma unroll
      for (int off = 32; off; off >>= 1) {
        mn = fminf(mn, __shfl_down(mn, off));
        mx = fmaxf(mx, __shfl_down(mx, off));
      }
      if (lane == 0) { smn[wq] = mn; smx[wq] = mx; }
    }
  }
  __syncthreads();
  if (t == 0) {
    if (isLoss) {
      atomicAdd(lacc, sred[0] + sred[1] + sred[2] + sred[3]);
    } else {
      float a = fminf(fminf(smn[0], smn[1]), fminf(smn[2], smn[3]));
      float b2 = fmaxf(fmaxf(smx[0], smx[1]), fmaxf(smx[2], smx[3]));
      atomicMin(&mm[0], mapf(a));
      atomicMax(&mm[1], mapf(b2));
    }
  }
}

// score on RAW rec2 (normalization folded into fuse): 32 blocks x 512
__global__ __launch_bounds__(512) void score_rec_k(
    const float* __restrict__ rec2, const float* __restrict__ wval,
    float* __restrict__ sraw) {
  __shared__ float sf[6160];
  const int b = blockIdx.x, t = threadIdx.x;
  const int half = t >> 8, px = t & 255;
  const int row = px >> 4, col = px & 15;
  float* myin = sf + half * 2880;
  float* mywv = sf + 5760 + half * 72;
  const float* src = rec2 + (size_t)b * 65536;
  for (int i = t; i < 5760; i += 512) sf[i] = 0.f;
  float acc = 0.f;
  for (int it = 0; it < 16; ++it) {
    int ic0 = half * 128 + it * 8;
    __syncthreads();
#pragma unroll
    for (int i = 0; i < 8; ++i)
      myin[i * 360 + (row + 1) * 20 + (col + 1)] = src[(ic0 + i) * 256 + px];
    if (px < 72) mywv[px] = wval[ic0 * 9 + px];
    __syncthreads();
#pragma unroll
    for (int i = 0; i < 8; ++i)
#pragma unroll
      for (int ky = 0; ky < 3; ++ky)
#pragma unroll
        for (int kx = 0; kx < 3; ++kx)
          acc += myin[i * 360 + (row + ky) * 20 + (col + kx)] * mywv[i * 9 + ky * 3 + kx];
  }
  __syncthreads();
  if (half == 1) sf[5904 + px] = acc;
  __syncthreads();
  if (half == 0) sraw[(size_t)b * 768 + px] = acc + sf[5904 + px];
}

__global__ void fuse_k(const float* __restrict__ cf, const float* __restrict__ rec2,
                       const float* __restrict__ sraw, const float* __restrict__ bval,
                       const unsigned* __restrict__ mm, const float* __restrict__ lacc,
                       const float* __restrict__ wsum9, float* __restrict__ outp) {
  const int idx = blockIdx.x * 256 + threadIdx.x;
  const int b = idx >> 16;
  const int rest = idx & 65535;
  const int pos = idx & 255;
  const float mn = unmapf(mm[0]), mx = unmapf(mm[1]);
  const float sc = 2.f / (mx - mn), sh = -mn * sc - 1.f;
  // de-normalized rec-score: conv(sc*rec+sh) = sc*conv(rec) + sh*P(pos)
  const int y = pos >> 4, x = pos & 15;
  float P = 0.f;
#pragma unroll
  for (int ky = 0; ky < 3; ++ky) {
    int yy = y + ky - 1;
    if (yy < 0 || yy > 15) continue;
#pragma unroll
    for (int kx = 0; kx < 3; ++kx) {
      int xx = x + kx - 1;
      if (xx < 0 || xx > 15) continue;
      P += wsum9[ky * 3 + kx];
    }
  }
  const float srec = sc * sraw[(size_t)b * 768 + pos] + sh * P;
  const float sc0 = sraw[(size_t)b * 768 + 256 + pos];
  const float sc1 = sraw[(size_t)b * 768 + 512 + pos];
  const float bv = bval[0];
  const float z0 = fmaxf(srec + sc0 + bv, 0.f);
  const float z1 = fmaxf(srec + sc1 + bv, 0.f);
  const float s0 = 1.f / (1.f + expf(-z0));
  const float s1 = 1.f / (1.f + expf(-z1));
  const float w0 = 1.f / (1.f + expf(s1 - s0));
  const float w1 = 1.f - w0;
  const float rn = fmaf(rec2[idx], sc, sh);
  const float f0 = cf[(size_t)b * 131072 + rest];
  const float f1 = cf[(size_t)b * 131072 + 65536 + rest];
  outp[idx] = 0.2f * (w0 * f0 + w1 * f1) + 0.8f * rn;
  if (idx == 0) outp[2097152] = lacc[0] * (1.f / 4194304.f);
}

extern "C" void kernel_launch(void* const* d_in, const int* in_sizes, int n_in,
                              void* d_out, int out_size, void* d_ws, size_t ws_size,
                              hipStream_t stream) {
  const float* cf    = (const float*)d_in[0];
  const float* fs    = (const float*)d_in[1];
  const float* fv    = (const float*)d_in[2];
  const float* fd    = (const float*)d_in[3];
  const float* w_enc = (const float*)d_in[4];
  const float* b_enc = (const float*)d_in[5];
  const float* w_dec = (const float*)d_in[6];
  const float* b_dec = (const float*)d_in[7];
  const float* w_val = (const float*)d_in[8];
  const float* b_val = (const float*)d_in[9];
  float* out = (float*)d_out;
  float* wsf = (float*)d_ws;

  // ws layout (float offsets); Xp and Midp must stay contiguous (halo blocks).
  unsigned short* Xp   = (unsigned short*)wsf;                  // 64 img padded NHWC
  unsigned short* Midp = (unsigned short*)(wsf + 2654208);      // 64 img
  unsigned short* Recp = (unsigned short*)(wsf + 5308416);      // 32 img
  float* rec2 = wsf + 6635520;                                  // 2,097,152 NCHW f32
  unsigned short* WrE = (unsigned short*)(wsf + 8732672);
  unsigned short* WrD = (unsigned short*)(wsf + 9027584);
  unsigned short* Ans = (unsigned short*)(wsf + 9322496);
  unsigned short* BmT = (unsigned short*)(wsf + 10371072);
  float* sraw = wsf + 11419648;                                 // 24,576
  float* wsum9 = wsf + 11444224;                                // 9
  float* lacc = wsf + 11444240;
  unsigned* mm = (unsigned*)(wsf + 11444241);

  prep_k<<<3937, 256, 0, stream>>>(cf, w_enc, w_dec, fv, fs, fd, w_val,
                                   Xp, WrE, WrD, Ans, BmT, Recp, wsum9, lacc, mm);
  encrec_k<<<448, 512, 0, stream>>>(Xp, WrE, b_enc, Midp, BmT, Ans, Recp,
                                    cf, w_val, sraw);
  conv_dec_k<<<384, 512, 0, stream>>>(Midp, Recp, WrD, b_dec, cf, rec2, lacc, mm);
  score_rec_k<<<32, 512, 0, stream>>>(rec2, w_val, sraw);
  fuse_k<<<8192, 256, 0, stream>>>(cf, rec2, sraw, b_val, mm, lacc, wsum9, out);
}